// Round 7
// baseline (299.269 us; speedup 1.0000x reference)
//
#include <hip/hip_runtime.h>
#include <hip/hip_bf16.h>
#include <math.h>

// ChordAwareTransformer bf16-MFMA pipeline, round 7.
//   Qcat=[pitch_q|harmony_q|voice_q] (d=192) vs Kcat=[k|chord_f|bass_f]
// R7 changes vs R6:
//  * gemm0 -> gemm_big: 256x256 tile, 512 thr (8 waves, 64x64 each), BK=32
//    double-buffered, 1 barrier/kt. Halves L2/L3 re-read traffic (640->320MB)
//    and doubles MFMA per barrier. 320 blocks all co-resident (2/CU).
//  * attn: 1024 thr (16 waves, 16 q each) -> 4 waves/SIMD (was 2): MFMA/VALU/
//    LDS phases of different waves overlap. LDS 96 KB (2x32KB K/V dbuf + 32KB P).
//  * fixed-max softmax kept (logit |max| <~5); XCD-local grid (bh major) kept.
// MFMA layouts (HW-verified, learn_hip m89/m91/m120):
//   A: [m=lane&15][k=quad*8+j]  B: [k=quad*8+j][n=lane&15]
//   C/D: [row=quad*4+reg][col=lane&15]

#define D_    1024
#define H_    16
#define B_    2
#define S_    2048
#define M_    (B_*S_)
#define NCAT_ 5120

#define QSCALE_ (1.44269504f / 24.0f)   // log2e * (1/sqrt(64)) / 3

typedef __attribute__((ext_vector_type(8))) short s16x8;
typedef __attribute__((ext_vector_type(4))) float f32x4;

__device__ __forceinline__ unsigned short f2bf(float f) {
    unsigned u = __builtin_bit_cast(unsigned, f);
    u += 0x7fff + ((u >> 16) & 1);          // RNE
    return (unsigned short)(u >> 16);
}
// packed f32x2 -> bf16x2 (v_cvt_pk_bf16_f32, RNE); low short = a
__device__ __forceinline__ unsigned pk2(float a, float b) {
    __hip_bfloat162 h = __float22bfloat162_rn(float2{a, b});
    unsigned r;
    __builtin_memcpy(&r, &h, 4);
    return r;
}

#define GLDS16(gp, lp) \
    __builtin_amdgcn_global_load_lds((const __attribute__((address_space(1))) void*)(gp), \
                                     (__attribute__((address_space(3))) void*)(lp), 16, 0, 0)

// ---------------------------------------------------------------- prep (fused)
struct PrepArgs {
    const float* x;
    const float* pitch_pc; const float* bass_pc;
    const float* Wc; const float* bc;
    const float* Wb; const float* bb;
    const float* wsrc[6]; unsigned short* wdst[6];
    const float* bsrc[5]; float* bias5;
    unsigned short* xb; unsigned short* cfb; unsigned short* bfb;
};

__global__ __launch_bounds__(256) void prep_kernel(PrepArgs a) {
    __shared__ unsigned short t[64][72];
    int bx = blockIdx.x;
    const int tid = threadIdx.x;

    if (bx < 4096) {                       // ---- cvt_x (fp32 -> bf16)
        int i = (bx * 256 + tid) * 4;
        float4 v = *(const float4*)(a.x + i);
        uint2 o = {pk2(v.x, v.y), pk2(v.z, v.w)};
        *(uint2*)(a.xb + i) = o;
        return;
    }
    bx -= 4096;
    if (bx < 1536) {                       // ---- wtrans (6 weights, 64x64 tiles)
        int z = bx >> 8, rem = bx & 255;
        const float* src = a.wsrc[z];
        unsigned short* dst = a.wdst[z];
        int k0 = (rem >> 4) * 64, n0 = (rem & 15) * 64;
        int r = tid >> 2, c0 = (tid & 3) * 16;
#pragma unroll
        for (int i = 0; i < 4; ++i) {
            float4 v = *(const float4*)(src + (size_t)(k0 + r) * 1024 + n0 + c0 + i * 4);
            ushort4 o = {f2bf(v.x), f2bf(v.y), f2bf(v.z), f2bf(v.w)};
            *(ushort4*)&t[r][c0 + i * 4] = o;
        }
        __syncthreads();
#pragma unroll
        for (int i = 0; i < 4; ++i) {
            ushort4 o = {t[c0 + i*4 + 0][r], t[c0 + i*4 + 1][r],
                         t[c0 + i*4 + 2][r], t[c0 + i*4 + 3][r]};
            *(ushort4*)(dst + (size_t)(n0 + r) * 1024 + k0 + c0 + i * 4) = o;
        }
        return;
    }
    bx -= 1536;
    if (bx < 20) {                         // ---- bpack
        int i = bx * 256 + tid;
        a.bias5[i] = a.bsrc[i >> 10][i & 1023];
        return;
    }
    bx -= 20;
    {                                      // ---- feat x2
        const float* pc;  const float* W;  const float* bias;  unsigned short* out;
        if (bx < 8192) { pc = a.pitch_pc; W = a.Wc; bias = a.bc; out = a.cfb; }
        else { bx -= 8192; pc = a.bass_pc; W = a.Wb; bias = a.bb; out = a.bfb; }
        int idx = bx * 256 + tid;
        int s = idx >> 10, c = idx & 1023;
        float acc = bias[c];
#pragma unroll
        for (int i = 0; i < 12; ++i)
            acc = fmaf(pc[s * 12 + i], W[i * 1024 + c], acc);
        out[idx] = f2bf(acc);
    }
}

// ---------------------------------------------------------------- gemm0 (big)
// C[4096 x 5120] = A @ Bt^T + bias. 256x256 tile, 512 thr = 8 waves (2x4),
// 64x64 per wave. BK=32, dbuf (2x32KB), one barrier/kt. Row = 4 chunks of
// 16 B; chunk at pos p holds source chunk p ^ ((row>>1)&3).
// wsel 0..2 scaled by QSCALE_, 3 plain, 4 -> transposed V to Vt.
__global__ __launch_bounds__(512) void gemm_big(
    const unsigned short* __restrict__ A, const unsigned short* __restrict__ Bt,
    const float* __restrict__ bias, unsigned short* __restrict__ Cb,
    unsigned short* __restrict__ Vt)
{
    __shared__ __align__(16) unsigned char lds[65536];   // buf0@0, buf1@32768
    const int tid = threadIdx.x;
    const int wv = tid >> 6, lane = tid & 63;
    const int lq = lane & 15, quad = lane >> 4;
    const int wm = wv >> 2, wn = wv & 3;                 // 2 x 4 wave grid
    const int m0 = blockIdx.y * 256, n0 = blockIdx.x * 256;

    // staging: lane l -> row (l>>2), chunk pos (l&3); source chunk
    // sc = (l&3) ^ ((row>>1)&3) = (l&3) ^ ((l>>3)&3). 4 rounds of 128 rows:
    // j0/j1 = A rows gr, gr+128; j2/j3 = B rows gr, gr+128.
    const int gr = wv * 16 + (lane >> 2);
    const int sc = (lane & 3) ^ ((lane >> 3) & 3);
    const unsigned short* pg[4];
    pg[0] = A  + (size_t)(m0 + gr) * 1024 + sc * 8;
    pg[1] = A  + (size_t)(m0 + gr + 128) * 1024 + sc * 8;
    pg[2] = Bt + (size_t)(n0 + gr) * 1024 + sc * 8;
    pg[3] = Bt + (size_t)(n0 + gr + 128) * 1024 + sc * 8;
    const unsigned lo[4] = {wv * 1024u, 8192u + wv * 1024u,
                            16384u + wv * 1024u, 24576u + wv * 1024u};

    f32x4 acc[8][4] = {};

    // prologue: stage tile 0 -> buf0
#pragma unroll
    for (int j = 0; j < 4; ++j) {
        GLDS16(pg[j], lds + lo[j]);
        pg[j] += 32;
    }

    for (int kt = 0; kt < 32; ++kt) {
        __syncthreads();   // stage(kt) drained; all waves done compute(kt-1)
        unsigned char* cur = lds + (kt & 1) * 32768;

        if (kt + 1 < 32) {   // stage(kt+1) -> other buf (overlaps compute)
            unsigned char* dst = lds + ((kt + 1) & 1) * 32768;
#pragma unroll
            for (int j = 0; j < 4; ++j) {
                GLDS16(pg[j], dst + lo[j]);
                pg[j] += 32;
            }
        }

        s16x8 aF[8], bF[4];
#pragma unroll
        for (int mi = 0; mi < 8; ++mi) {
            int row = wm * 128 + mi * 16 + lq;
            aF[mi] = *(const s16x8*)(cur + row * 64 + ((quad ^ ((row >> 1) & 3)) * 16));
        }
#pragma unroll
        for (int ni = 0; ni < 4; ++ni) {
            int row = wn * 64 + ni * 16 + lq;
            bF[ni] = *(const s16x8*)(cur + 16384 + row * 64 + ((quad ^ ((row >> 1) & 3)) * 16));
        }
#pragma unroll
        for (int mi = 0; mi < 8; ++mi)
#pragma unroll
            for (int ni = 0; ni < 4; ++ni)
                acc[mi][ni] = __builtin_amdgcn_mfma_f32_16x16x32_bf16(
                    aF[mi], bF[ni], acc[mi][ni], 0, 0, 0);
    }

    const int wsel = n0 >> 10;
    const float sc2 = (wsel <= 2) ? QSCALE_ : 1.0f;
#pragma unroll
    for (int ni = 0; ni < 4; ++ni) {
        int n = n0 + wn * 64 + ni * 16 + lq;
        float bv = bias[n];
        if (wsel == 4) {
            int nl = n - 4096, h = nl >> 6, d = nl & 63;
#pragma unroll
            for (int mi = 0; mi < 8; ++mi) {
                int mrow = m0 + wm * 128 + mi * 16 + quad * 4;
                uint2 w = {pk2(acc[mi][ni][0] + bv, acc[mi][ni][1] + bv),
                           pk2(acc[mi][ni][2] + bv, acc[mi][ni][3] + bv)};
                *(uint2*)(Vt + ((size_t)h * 64 + d) * (size_t)M_ + mrow) = w;
            }
        } else {
#pragma unroll
            for (int mi = 0; mi < 8; ++mi) {
                int mrow = m0 + wm * 128 + mi * 16 + quad * 4;
#pragma unroll
                for (int r = 0; r < 4; ++r)
                    Cb[(size_t)(mrow + r) * NCAT_ + n] = f2bf((acc[mi][ni][r] + bv) * sc2);
            }
        }
    }
}

// ---------------------------------------------------------------- gemm_out
// out[4096 x 1024] fp32 = ctx @ Wot^T + bo. 128x128 tile, R6 structure.
__global__ __launch_bounds__(256) void gemm_out(
    const unsigned short* __restrict__ A, const unsigned short* __restrict__ Bt,
    const float* __restrict__ bias, float* __restrict__ Cf)
{
    __shared__ __align__(16) unsigned char lds[32768];   // buf0@0, buf1@16384
    const int tid = threadIdx.x;
    const int wv = tid >> 6, lane = tid & 63;
    const int lq = lane & 15, quad = lane >> 4;
    const int wm = wv >> 1, wn = wv & 1;
    const int m0 = blockIdx.y * 128, n0 = blockIdx.x * 128;

    const int sr = lane >> 2;
    const int sc = (lane & 3) ^ ((lane >> 3) & 3);
    const unsigned short* Abase = A + (size_t)m0 * 1024 + sc * 8;
    const unsigned short* Bbase = Bt + (size_t)n0 * 1024 + sc * 8;

    f32x4 acc[4][4] = {};

#pragma unroll
    for (int j = 0; j < 2; ++j) {
        int seg = wv * 2 + j;
        GLDS16(Abase + (size_t)(seg * 16 + sr) * 1024, lds + seg * 1024);
        GLDS16(Bbase + (size_t)(seg * 16 + sr) * 1024, lds + 8192 + seg * 1024);
    }

    for (int kt = 0; kt < 32; ++kt) {
        __syncthreads();
        unsigned char* cur = lds + (kt & 1) * 16384;

        if (kt + 1 < 32) {
            const int k0n = (kt + 1) * 32;
            unsigned char* dst = lds + ((kt + 1) & 1) * 16384;
#pragma unroll
            for (int j = 0; j < 2; ++j) {
                int seg = wv * 2 + j;
                GLDS16(Abase + (size_t)(seg * 16 + sr) * 1024 + k0n, dst + seg * 1024);
                GLDS16(Bbase + (size_t)(seg * 16 + sr) * 1024 + k0n, dst + 8192 + seg * 1024);
            }
        }

        s16x8 aF[4], bF[4];
#pragma unroll
        for (int mi = 0; mi < 4; ++mi) {
            int row = wm * 64 + mi * 16 + lq;
            aF[mi] = *(const s16x8*)(cur + row * 64 + ((quad ^ ((row >> 1) & 3)) * 16));
        }
#pragma unroll
        for (int ni = 0; ni < 4; ++ni) {
            int row = wn * 64 + ni * 16 + lq;
            bF[ni] = *(const s16x8*)(cur + 8192 + row * 64 + ((quad ^ ((row >> 1) & 3)) * 16));
        }
#pragma unroll
        for (int mi = 0; mi < 4; ++mi)
#pragma unroll
            for (int ni = 0; ni < 4; ++ni)
                acc[mi][ni] = __builtin_amdgcn_mfma_f32_16x16x32_bf16(
                    aF[mi], bF[ni], acc[mi][ni], 0, 0, 0);
    }

#pragma unroll
    for (int ni = 0; ni < 4; ++ni) {
        int n = n0 + wn * 64 + ni * 16 + lq;
        float bv = bias[n];
#pragma unroll
        for (int mi = 0; mi < 4; ++mi) {
            int mrow = m0 + wm * 64 + mi * 16 + quad * 4;
#pragma unroll
            for (int r = 0; r < 4; ++r)
                Cf[(size_t)(mrow + r) * 1024 + n] = acc[mi][ni][r] + bv;
        }
    }
}

// ---------------------------------------------------------------- attention
// Block: one (b,h), 256 queries, 1024 thr (16 waves x 16 q) -> 4 waves/SIMD.
// 32 K-tiles of 64. LDS (98304 B): buf0@0, buf1@32768 (K 3x8192 + V 8192
// @24576); P@65536 [256 q][64 k] bf16, chunk c at pos c^(q&7). Q staging
// (96 KB) overlays before the K-loop. One barrier/kt, stage(t+1) post-barrier.
// P rows wave-private (wave w owns q in [16w,16w+16)): no P barrier.
// Grid (bh, qchunk): all 8 q-chunks of a bh share an XCD (id%8 = bh%8).
#define ATQ_ 256

__global__ __launch_bounds__(1024) void attn_kernel(
    const unsigned short* __restrict__ Q5b, const unsigned short* __restrict__ cfb,
    const unsigned short* __restrict__ bfb, const unsigned short* __restrict__ Vtg,
    unsigned short* __restrict__ ctxb)
{
    extern __shared__ __align__(16) unsigned char smem[];
    const int tid = threadIdx.x;
    const int wv = tid >> 6, lane = tid & 63;   // wv 0..15
    const int lq = lane & 15, quad = lane >> 4;
    const int bh = blockIdx.x;
    const int b = bh >> 4, h = bh & 15;
    const int q0 = blockIdx.y * ATQ_;
    const int lr = lane >> 3;
    const int g = (lane & 7) ^ lr;

    // ---- hoisted K/V staging pointers: 2 slots per thread (32 total/tile)
    const unsigned short* sp[2];
    size_t sstr[2];
    unsigned lofs[2];
#pragma unroll
    for (int i = 0; i < 2; ++i) {
        int t = wv * 2 + i;
        if (t < 8) {
            sp[i] = Q5b + (size_t)(b * S_ + t * 8 + lr) * NCAT_ + 3072 + h * 64 + g * 8;
            sstr[i] = (size_t)64 * NCAT_;
        } else if (t < 16) {
            sp[i] = cfb + (size_t)((t - 8) * 8 + lr) * 1024 + h * 64 + g * 8;
            sstr[i] = 64 * 1024;
        } else if (t < 24) {
            sp[i] = bfb + (size_t)((t - 16) * 8 + lr) * 1024 + h * 64 + g * 8;
            sstr[i] = 64 * 1024;
        } else {
            sp[i] = Vtg + (size_t)(h * 64 + (t - 24) * 8 + lr) * (size_t)M_ + b * S_ + g * 8;
            sstr[i] = 64;
        }
        lofs[i] = t * 1024;
    }

    // ---- stage Q: 3 segs x 32 rowblocks = 96 KB (16 waves x 6 blocks)
#pragma unroll
    for (int i = 0; i < 6; ++i) {
        int t = wv * 6 + i;
        int seg = t >> 5, rb = t & 31;
        const unsigned short* src = Q5b + (size_t)(b * S_ + q0 + rb * 8 + lr) * NCAT_
                                    + seg * 1024 + h * 64 + g * 8;
        GLDS16(src, smem + seg * 32768 + rb * 1024);
    }
    __syncthreads();

    s16x8 qf[6];
    {
        int row = wv * 16 + lq;
#pragma unroll
        for (int ds = 0; ds < 6; ++ds) {
            int pos = ((ds & 1) * 4 + quad) ^ (row & 7);
            qf[ds] = *(const s16x8*)(smem + (ds >> 1) * 32768 + row * 128 + pos * 16);
        }
    }
    __syncthreads();   // qf reads drained before buf0 staging overwrites

    f32x4 o[4] = {};
    float lpart = 0.f;
    unsigned char* Pb = smem + 65536;

    // ---- prologue: stage tile 0 -> buf0
#pragma unroll
    for (int i = 0; i < 2; ++i) {
        GLDS16(sp[i], smem + lofs[i]);
        sp[i] += sstr[i];
    }

    for (int kt = 0; kt < 32; ++kt) {
        __syncthreads();   // stage(kt) drained; all waves past compute(kt-1)
        unsigned char* cur = smem + (kt & 1) * 32768;

        if (kt + 1 < 32) {   // stage(kt+1) -> other buf (overlaps compute)
            unsigned char* dst = smem + ((kt + 1) & 1) * 32768;
#pragma unroll
            for (int i = 0; i < 2; ++i) {
                GLDS16(sp[i], dst + lofs[i]);
                sp[i] += sstr[i];
            }
        }

        // ---- scores S^T = K * Q^T  (A=K frag, B=Q frag); q = wv*16+lq
        f32x4 st[4] = {};
#pragma unroll
        for (int ka = 0; ka < 4; ++ka) {
            int key = ka * 16 + lq;
#pragma unroll
            for (int ds = 0; ds < 6; ++ds) {
                int pos = ((ds & 1) * 4 + quad) ^ (key & 7);
                s16x8 kf = *(const s16x8*)(cur + (ds >> 1) * 8192 + key * 128 + pos * 16);
                st[ka] = __builtin_amdgcn_mfma_f32_16x16x32_bf16(
                    kf, qf[ds], st[ka], 0, 0, 0);
            }
        }

        // ---- fixed-max softmax; P[q][k] bf16 via packed cvt
#pragma unroll
        for (int ka = 0; ka < 4; ++ka) {
            float p0 = exp2f(st[ka][0]);
            float p1 = exp2f(st[ka][1]);
            float p2 = exp2f(st[ka][2]);
            float p3 = exp2f(st[ka][3]);
            lpart += (p0 + p1) + (p2 + p3);
            int q = wv * 16 + lq;
            int c = ka * 2 + (quad >> 1);
            unsigned char* pp = Pb + q * 128 + ((c ^ (q & 7)) * 16) + (quad & 1) * 8;
            uint2 w = {pk2(p0, p1), pk2(p2, p3)};
            *(uint2*)pp = w;
        }

        // ---- PV: O += P @ V   (A=P from LDS, B=V^T rows d)
        {
            int q = wv * 16 + lq;
            s16x8 pA[2];
#pragma unroll
            for (int kk = 0; kk < 2; ++kk) {
                int pos = (kk * 4 + quad) ^ (q & 7);
                pA[kk] = *(const s16x8*)(Pb + q * 128 + pos * 16);
            }
#pragma unroll
            for (int ni = 0; ni < 4; ++ni) {
                int d = ni * 16 + lq;
#pragma unroll
                for (int kk = 0; kk < 2; ++kk) {
                    int pos = (kk * 4 + quad) ^ (d & 7);
                    s16x8 vB = *(const s16x8*)(cur + 24576 + d * 128 + pos * 16);
                    o[ni] = __builtin_amdgcn_mfma_f32_16x16x32_bf16(
                        pA[kk], vB, o[ni], 0, 0, 0);
                }
            }
        }
    }

    // ---- epilogue: l is lq-indexed (q=wv*16+lq); O rows are quad*4+r
    {
        float l = lpart;
        l += __shfl_xor(l, 16);
        l += __shfl_xor(l, 32);
        float inv = 1.0f / l;
        float invr[4];
#pragma unroll
        for (int r = 0; r < 4; ++r)
            invr[r] = __shfl(inv, quad * 4 + r);
#pragma unroll
        for (int r = 0; r < 4; ++r) {
            int row = q0 + wv * 16 + quad * 4 + r;
#pragma unroll
            for (int ni = 0; ni < 4; ++ni)
                ctxb[(size_t)(b * S_ + row) * 1024 + h * 64 + ni * 16 + lq] =
                    f2bf(o[ni][r] * invr[r]);
        }
    }
}

// ---------------------------------------------------------------- launch
extern "C" void kernel_launch(void* const* d_in, const int* in_sizes, int n_in,
                              void* d_out, int out_size, void* d_ws, size_t ws_size,
                              hipStream_t stream)
{
    const float* x        = (const float*)d_in[0];
    const float* pitch_pc = (const float*)d_in[1];
    const float* bass_pc  = (const float*)d_in[2];
    const float* Wpq = (const float*)d_in[3];   const float* bpq = (const float*)d_in[4];
    const float* Whq = (const float*)d_in[5];   const float* bhq = (const float*)d_in[6];
    const float* Wvq = (const float*)d_in[7];   const float* bvq = (const float*)d_in[8];
    const float* Wk  = (const float*)d_in[9];   const float* bk  = (const float*)d_in[10];
    const float* Wv  = (const float*)d_in[11];  const float* bv  = (const float*)d_in[12];
    const float* Wo  = (const float*)d_in[13];  const float* bo  = (const float*)d_in[14];
    const float* Wc  = (const float*)d_in[15];  const float* bc  = (const float*)d_in[16];
    const float* Wb  = (const float*)d_in[17];  const float* bb  = (const float*)d_in[18];

    char* ws = (char*)d_ws;
    unsigned short* xb   = (unsigned short*)(ws);                      // 8 MB
    unsigned short* W5t  = (unsigned short*)(ws + 8388608);            // 10 MB
    unsigned short* Wot  = (unsigned short*)(ws + 18874368);           // 2 MB
    float*          bias5= (float*)         (ws + 20971520);           // 20 KB
    unsigned short* cfb  = (unsigned short*)(ws + 20992000);           // 4 MB
    unsigned short* bfb  = (unsigned short*)(ws + 25186304);           // 4 MB
    unsigned short* Q5b  = (unsigned short*)(ws + 29380608);           // 40 MB
    unsigned short* Vtg  = (unsigned short*)(ws + 71323648);           // 8 MB
    unsigned short* ctxb = (unsigned short*)(ws + 79712256);           // 8 MB

    PrepArgs pa;
    pa.x = x; pa.pitch_pc = pitch_pc; pa.bass_pc = bass_pc;
    pa.Wc = Wc; pa.bc = bc; pa.Wb = Wb; pa.bb = bb;
    pa.wsrc[0] = Wpq; pa.wsrc[1] = Whq; pa.wsrc[2] = Wvq;
    pa.wsrc[3] = Wk;  pa.wsrc[4] = Wv;  pa.wsrc[5] = Wo;
    for (int i = 0; i < 5; ++i) pa.wdst[i] = W5t + (size_t)i * 1024 * 1024;
    pa.wdst[5] = Wot;
    pa.bsrc[0] = bpq; pa.bsrc[1] = bhq; pa.bsrc[2] = bvq; pa.bsrc[3] = bk; pa.bsrc[4] = bv;
    pa.bias5 = bias5; pa.xb = xb; pa.cfb = cfb; pa.bfb = bfb;

    prep_kernel<<<dim3(4096 + 1536 + 20 + 8192 + 8192), 256, 0, stream>>>(pa);

    gemm_big<<<dim3(20, 16), 512, 0, stream>>>(xb, W5t, bias5, Q5b, Vtg);

    attn_kernel<<<dim3(B_ * H_, S_ / ATQ_), 1024, 98304, stream>>>(Q5b, cfb, bfb, Vtg, ctxb);

    gemm_out<<<dim3(8, 32), 256, 0, stream>>>(ctxb, Wot, bo, (float*)d_out);
}

// Round 8
// 280.268 us; speedup vs baseline: 1.0678x; 1.0678x over previous
//
#include <hip/hip_runtime.h>
#include <hip/hip_bf16.h>
#include <math.h>

// ChordAwareTransformer bf16-MFMA pipeline, round 8.
//   Qcat=[pitch_q|harmony_q|voice_q] (d=192) vs Kcat=[k|chord_f|bass_f]
// R8 changes vs R7:
//  * attn ATQ=128, 512 thr (8 waves), LDS 80 KB -> 2 blocks/CU: two
//    independent barrier domains per CU so one block's serial softmax/barrier
//    phase overlaps the other block's MFMA phase (R7's single 16-wave domain
//    aligned all waves' phases -> 45% idle cycles).
//  * exp2 via __builtin_amdgcn_exp2f (raw v_exp_f32) when available.
//  * gemm0 reverted to R6 128x128 gemm_k (256x256 big tile was -17 us).
// MFMA layouts (HW-verified, learn_hip m89/m91/m120):
//   A: [m=lane&15][k=quad*8+j]  B: [k=quad*8+j][n=lane&15]
//   C/D: [row=quad*4+reg][col=lane&15]

#define D_    1024
#define H_    16
#define B_    2
#define S_    2048
#define M_    (B_*S_)
#define NCAT_ 5120

#define QSCALE_ (1.44269504f / 24.0f)   // log2e * (1/sqrt(64)) / 3

#if __has_builtin(__builtin_amdgcn_exp2f)
#define EXP2(x) __builtin_amdgcn_exp2f(x)
#else
#define EXP2(x) exp2f(x)
#endif

typedef __attribute__((ext_vector_type(8))) short s16x8;
typedef __attribute__((ext_vector_type(4))) float f32x4;

__device__ __forceinline__ unsigned short f2bf(float f) {
    unsigned u = __builtin_bit_cast(unsigned, f);
    u += 0x7fff + ((u >> 16) & 1);          // RNE
    return (unsigned short)(u >> 16);
}
// packed f32x2 -> bf16x2 (v_cvt_pk_bf16_f32, RNE); low short = a
__device__ __forceinline__ unsigned pk2(float a, float b) {
    __hip_bfloat162 h = __float22bfloat162_rn(float2{a, b});
    unsigned r;
    __builtin_memcpy(&r, &h, 4);
    return r;
}

#define GLDS16(gp, lp) \
    __builtin_amdgcn_global_load_lds((const __attribute__((address_space(1))) void*)(gp), \
                                     (__attribute__((address_space(3))) void*)(lp), 16, 0, 0)

// ---------------------------------------------------------------- prep (fused)
struct PrepArgs {
    const float* x;
    const float* pitch_pc; const float* bass_pc;
    const float* Wc; const float* bc;
    const float* Wb; const float* bb;
    const float* wsrc[6]; unsigned short* wdst[6];
    const float* bsrc[5]; float* bias5;
    unsigned short* xb; unsigned short* cfb; unsigned short* bfb;
};

__global__ __launch_bounds__(256) void prep_kernel(PrepArgs a) {
    __shared__ unsigned short t[64][72];
    int bx = blockIdx.x;
    const int tid = threadIdx.x;

    if (bx < 4096) {                       // ---- cvt_x (fp32 -> bf16)
        int i = (bx * 256 + tid) * 4;
        float4 v = *(const float4*)(a.x + i);
        uint2 o = {pk2(v.x, v.y), pk2(v.z, v.w)};
        *(uint2*)(a.xb + i) = o;
        return;
    }
    bx -= 4096;
    if (bx < 1536) {                       // ---- wtrans (6 weights, 64x64 tiles)
        int z = bx >> 8, rem = bx & 255;
        const float* src = a.wsrc[z];
        unsigned short* dst = a.wdst[z];
        int k0 = (rem >> 4) * 64, n0 = (rem & 15) * 64;
        int r = tid >> 2, c0 = (tid & 3) * 16;
#pragma unroll
        for (int i = 0; i < 4; ++i) {
            float4 v = *(const float4*)(src + (size_t)(k0 + r) * 1024 + n0 + c0 + i * 4);
            ushort4 o = {f2bf(v.x), f2bf(v.y), f2bf(v.z), f2bf(v.w)};
            *(ushort4*)&t[r][c0 + i * 4] = o;
        }
        __syncthreads();
#pragma unroll
        for (int i = 0; i < 4; ++i) {
            ushort4 o = {t[c0 + i*4 + 0][r], t[c0 + i*4 + 1][r],
                         t[c0 + i*4 + 2][r], t[c0 + i*4 + 3][r]};
            *(ushort4*)(dst + (size_t)(n0 + r) * 1024 + k0 + c0 + i * 4) = o;
        }
        return;
    }
    bx -= 1536;
    if (bx < 20) {                         // ---- bpack
        int i = bx * 256 + tid;
        a.bias5[i] = a.bsrc[i >> 10][i & 1023];
        return;
    }
    bx -= 20;
    {                                      // ---- feat x2
        const float* pc;  const float* W;  const float* bias;  unsigned short* out;
        if (bx < 8192) { pc = a.pitch_pc; W = a.Wc; bias = a.bc; out = a.cfb; }
        else { bx -= 8192; pc = a.bass_pc; W = a.Wb; bias = a.bb; out = a.bfb; }
        int idx = bx * 256 + tid;
        int s = idx >> 10, c = idx & 1023;
        float acc = bias[c];
#pragma unroll
        for (int i = 0; i < 12; ++i)
            acc = fmaf(pc[s * 12 + i], W[i * 1024 + c], acc);
        out[idx] = f2bf(acc);
    }
}

// ---------------------------------------------------------------- MFMA GEMM
// C[M x N] = A[M x 1024] @ Bt^T + bias.  BK=32, double-buffered, one barrier
// per K-tile. Per buffer: A 128x32 bf16 (8 KB) @0, B @8192. Row = 4 chunks of
// 16 B; chunk at pos p holds source chunk p ^ ((row>>1)&3).
// MODE 0: N=5120; wsel 0..2 scaled by QSCALE_, wsel 3 plain, wsel 4 -> Vt^T.
// MODE 1: N=1024, fp32 out.
template<int MODE>
__global__ __launch_bounds__(256) void gemm_k(
    const unsigned short* __restrict__ A, const unsigned short* __restrict__ Bt,
    const float* __restrict__ bias, unsigned short* __restrict__ Cb,
    unsigned short* __restrict__ Vt, float* __restrict__ Cf)
{
    __shared__ __align__(16) unsigned char lds[32768];   // buf0@0, buf1@16384
    const int tid = threadIdx.x;
    const int wv = tid >> 6, lane = tid & 63;
    const int lq = lane & 15, quad = lane >> 4;
    const int wm = wv >> 1, wn = wv & 1;
    const int m0 = blockIdx.y * 128, n0 = blockIdx.x * 128;

    const int sr = lane >> 2;
    const int sc = (lane & 3) ^ ((lane >> 3) & 3);
    const unsigned short* Abase = A + (size_t)m0 * 1024 + sc * 8;
    const unsigned short* Bbase = Bt + (size_t)n0 * 1024 + sc * 8;

    f32x4 acc[4][4] = {};

    // prologue: stage tile 0 -> buf0
#pragma unroll
    for (int j = 0; j < 2; ++j) {
        int seg = wv * 2 + j;
        GLDS16(Abase + (size_t)(seg * 16 + sr) * 1024, lds + seg * 1024);
        GLDS16(Bbase + (size_t)(seg * 16 + sr) * 1024, lds + 8192 + seg * 1024);
    }

    for (int kt = 0; kt < 32; ++kt) {
        __syncthreads();   // stage(kt) drained; all waves done compute(kt-1)
        unsigned char* cur = lds + (kt & 1) * 16384;

        if (kt + 1 < 32) {   // stage(kt+1) -> other buf (overlaps compute)
            const int k0n = (kt + 1) * 32;
            unsigned char* dst = lds + ((kt + 1) & 1) * 16384;
#pragma unroll
            for (int j = 0; j < 2; ++j) {
                int seg = wv * 2 + j;
                GLDS16(Abase + (size_t)(seg * 16 + sr) * 1024 + k0n, dst + seg * 1024);
                GLDS16(Bbase + (size_t)(seg * 16 + sr) * 1024 + k0n, dst + 8192 + seg * 1024);
            }
        }

        s16x8 aF[4], bF[4];
#pragma unroll
        for (int mi = 0; mi < 4; ++mi) {
            int row = wm * 64 + mi * 16 + lq;
            aF[mi] = *(const s16x8*)(cur + row * 64 + ((quad ^ ((row >> 1) & 3)) * 16));
        }
#pragma unroll
        for (int ni = 0; ni < 4; ++ni) {
            int row = wn * 64 + ni * 16 + lq;
            bF[ni] = *(const s16x8*)(cur + 8192 + row * 64 + ((quad ^ ((row >> 1) & 3)) * 16));
        }
#pragma unroll
        for (int mi = 0; mi < 4; ++mi)
#pragma unroll
            for (int ni = 0; ni < 4; ++ni)
                acc[mi][ni] = __builtin_amdgcn_mfma_f32_16x16x32_bf16(
                    aF[mi], bF[ni], acc[mi][ni], 0, 0, 0);
    }

    if (MODE == 0) {
        const int wsel = n0 >> 10;
        const float sc2 = (wsel <= 2) ? QSCALE_ : 1.0f;
#pragma unroll
        for (int ni = 0; ni < 4; ++ni) {
            int n = n0 + wn * 64 + ni * 16 + lq;
            float bv = bias[n];
            if (wsel == 4) {
                int nl = n - 4096, h = nl >> 6, d = nl & 63;
#pragma unroll
                for (int mi = 0; mi < 4; ++mi) {
                    int mrow = m0 + wm * 64 + mi * 16 + quad * 4;
                    uint2 w = {pk2(acc[mi][ni][0] + bv, acc[mi][ni][1] + bv),
                               pk2(acc[mi][ni][2] + bv, acc[mi][ni][3] + bv)};
                    *(uint2*)(Vt + ((size_t)h * 64 + d) * (size_t)M_ + mrow) = w;
                }
            } else {
#pragma unroll
                for (int mi = 0; mi < 4; ++mi) {
                    int mrow = m0 + wm * 64 + mi * 16 + quad * 4;
#pragma unroll
                    for (int r = 0; r < 4; ++r)
                        Cb[(size_t)(mrow + r) * NCAT_ + n] = f2bf((acc[mi][ni][r] + bv) * sc2);
                }
            }
        }
    } else {
#pragma unroll
        for (int ni = 0; ni < 4; ++ni) {
            int n = n0 + wn * 64 + ni * 16 + lq;
            float bv = bias[n];
#pragma unroll
            for (int mi = 0; mi < 4; ++mi) {
                int mrow = m0 + wm * 64 + mi * 16 + quad * 4;
#pragma unroll
                for (int r = 0; r < 4; ++r)
                    Cf[(size_t)(mrow + r) * 1024 + n] = acc[mi][ni][r] + bv;
            }
        }
    }
}

// ---------------------------------------------------------------- attention
// Block: one (b,h), 128 queries, 512 thr (8 waves x 16 q). 32 K-tiles of 64.
// LDS (81920 B): buf0@0, buf1@32768 (K 3x8192 + V 8192@24576); P@65536
// [128 q][64 k] bf16, chunk c at pos c^(q&7). Q staging (48 KB) overlays
// before the K-loop. One barrier/kt, stage(t+1) post-barrier.
// 2 blocks/CU -> two independent barrier domains overlap each other's
// serial phases. P rows wave-private: no P barrier.
// Grid (bh, qchunk): all q-chunks of a bh share an XCD (id%8 = bh%8).
#define ATQ_ 128

__global__ __launch_bounds__(512, 4) void attn_kernel(
    const unsigned short* __restrict__ Q5b, const unsigned short* __restrict__ cfb,
    const unsigned short* __restrict__ bfb, const unsigned short* __restrict__ Vtg,
    unsigned short* __restrict__ ctxb)
{
    extern __shared__ __align__(16) unsigned char smem[];
    const int tid = threadIdx.x;
    const int wv = tid >> 6, lane = tid & 63;   // wv 0..7
    const int lq = lane & 15, quad = lane >> 4;
    const int bh = blockIdx.x;
    const int b = bh >> 4, h = bh & 15;
    const int q0 = blockIdx.y * ATQ_;
    const int lr = lane >> 3;
    const int g = (lane & 7) ^ lr;

    // ---- hoisted K/V staging pointers: 4 slots per thread (32 total/tile)
    const unsigned short* sp[4];
    size_t sstr[4];
    unsigned lofs[4];
#pragma unroll
    for (int i = 0; i < 4; ++i) {
        int t = wv * 4 + i;
        if (t < 8) {
            sp[i] = Q5b + (size_t)(b * S_ + t * 8 + lr) * NCAT_ + 3072 + h * 64 + g * 8;
            sstr[i] = (size_t)64 * NCAT_;
        } else if (t < 16) {
            sp[i] = cfb + (size_t)((t - 8) * 8 + lr) * 1024 + h * 64 + g * 8;
            sstr[i] = 64 * 1024;
        } else if (t < 24) {
            sp[i] = bfb + (size_t)((t - 16) * 8 + lr) * 1024 + h * 64 + g * 8;
            sstr[i] = 64 * 1024;
        } else {
            sp[i] = Vtg + (size_t)(h * 64 + (t - 24) * 8 + lr) * (size_t)M_ + b * S_ + g * 8;
            sstr[i] = 64;
        }
        lofs[i] = t * 1024;
    }

    // ---- stage Q: 3 segs x 16 rowblocks = 48 KB (8 waves x 6 blocks)
#pragma unroll
    for (int i = 0; i < 6; ++i) {
        int t = wv * 6 + i;
        int seg = t >> 4, rb = t & 15;
        const unsigned short* src = Q5b + (size_t)(b * S_ + q0 + rb * 8 + lr) * NCAT_
                                    + seg * 1024 + h * 64 + g * 8;
        GLDS16(src, smem + seg * 16384 + rb * 1024);
    }
    __syncthreads();

    s16x8 qf[6];
    {
        int row = wv * 16 + lq;
#pragma unroll
        for (int ds = 0; ds < 6; ++ds) {
            int pos = ((ds & 1) * 4 + quad) ^ (row & 7);
            qf[ds] = *(const s16x8*)(smem + (ds >> 1) * 16384 + row * 128 + pos * 16);
        }
    }
    __syncthreads();   // qf reads drained before buf0 staging overwrites

    f32x4 o[4] = {};
    float lpart = 0.f;
    unsigned char* Pb = smem + 65536;

    // ---- prologue: stage tile 0 -> buf0
#pragma unroll
    for (int i = 0; i < 4; ++i) {
        GLDS16(sp[i], smem + lofs[i]);
        sp[i] += sstr[i];
    }

    for (int kt = 0; kt < 32; ++kt) {
        __syncthreads();   // stage(kt) drained; all waves past compute(kt-1)
        unsigned char* cur = smem + (kt & 1) * 32768;

        if (kt + 1 < 32) {   // stage(kt+1) -> other buf (overlaps compute)
            unsigned char* dst = smem + ((kt + 1) & 1) * 32768;
#pragma unroll
            for (int i = 0; i < 4; ++i) {
                GLDS16(sp[i], dst + lofs[i]);
                sp[i] += sstr[i];
            }
        }

        // ---- scores S^T = K * Q^T  (A=K frag, B=Q frag); q = wv*16+lq
        f32x4 st[4] = {};
#pragma unroll
        for (int ka = 0; ka < 4; ++ka) {
            int key = ka * 16 + lq;
#pragma unroll
            for (int ds = 0; ds < 6; ++ds) {
                int pos = ((ds & 1) * 4 + quad) ^ (key & 7);
                s16x8 kf = *(const s16x8*)(cur + (ds >> 1) * 8192 + key * 128 + pos * 16);
                st[ka] = __builtin_amdgcn_mfma_f32_16x16x32_bf16(
                    kf, qf[ds], st[ka], 0, 0, 0);
            }
        }

        // ---- fixed-max softmax; P[q][k] bf16 via packed cvt
#pragma unroll
        for (int ka = 0; ka < 4; ++ka) {
            float p0 = EXP2(st[ka][0]);
            float p1 = EXP2(st[ka][1]);
            float p2 = EXP2(st[ka][2]);
            float p3 = EXP2(st[ka][3]);
            lpart += (p0 + p1) + (p2 + p3);
            int q = wv * 16 + lq;
            int c = ka * 2 + (quad >> 1);
            unsigned char* pp = Pb + q * 128 + ((c ^ (q & 7)) * 16) + (quad & 1) * 8;
            uint2 w = {pk2(p0, p1), pk2(p2, p3)};
            *(uint2*)pp = w;
        }

        // ---- PV: O += P @ V   (A=P from LDS, B=V^T rows d)
        {
            int q = wv * 16 + lq;
            s16x8 pA[2];
#pragma unroll
            for (int kk = 0; kk < 2; ++kk) {
                int pos = (kk * 4 + quad) ^ (q & 7);
                pA[kk] = *(const s16x8*)(Pb + q * 128 + pos * 16);
            }
#pragma unroll
            for (int ni = 0; ni < 4; ++ni) {
                int d = ni * 16 + lq;
#pragma unroll
                for (int kk = 0; kk < 2; ++kk) {
                    int pos = (kk * 4 + quad) ^ (d & 7);
                    s16x8 vB = *(const s16x8*)(cur + 24576 + d * 128 + pos * 16);
                    o[ni] = __builtin_amdgcn_mfma_f32_16x16x32_bf16(
                        pA[kk], vB, o[ni], 0, 0, 0);
                }
            }
        }
    }

    // ---- epilogue: l is lq-indexed (q=wv*16+lq); O rows are quad*4+r
    {
        float l = lpart;
        l += __shfl_xor(l, 16);
        l += __shfl_xor(l, 32);
        float inv = 1.0f / l;
        float invr[4];
#pragma unroll
        for (int r = 0; r < 4; ++r)
            invr[r] = __shfl(inv, quad * 4 + r);
#pragma unroll
        for (int r = 0; r < 4; ++r) {
            int row = q0 + wv * 16 + quad * 4 + r;
#pragma unroll
            for (int ni = 0; ni < 4; ++ni)
                ctxb[(size_t)(b * S_ + row) * 1024 + h * 64 + ni * 16 + lq] =
                    f2bf(o[ni][r] * invr[r]);
        }
    }
}

// ---------------------------------------------------------------- launch
extern "C" void kernel_launch(void* const* d_in, const int* in_sizes, int n_in,
                              void* d_out, int out_size, void* d_ws, size_t ws_size,
                              hipStream_t stream)
{
    const float* x        = (const float*)d_in[0];
    const float* pitch_pc = (const float*)d_in[1];
    const float* bass_pc  = (const float*)d_in[2];
    const float* Wpq = (const float*)d_in[3];   const float* bpq = (const float*)d_in[4];
    const float* Whq = (const float*)d_in[5];   const float* bhq = (const float*)d_in[6];
    const float* Wvq = (const float*)d_in[7];   const float* bvq = (const float*)d_in[8];
    const float* Wk  = (const float*)d_in[9];   const float* bk  = (const float*)d_in[10];
    const float* Wv  = (const float*)d_in[11];  const float* bv  = (const float*)d_in[12];
    const float* Wo  = (const float*)d_in[13];  const float* bo  = (const float*)d_in[14];
    const float* Wc  = (const float*)d_in[15];  const float* bc  = (const float*)d_in[16];
    const float* Wb  = (const float*)d_in[17];  const float* bb  = (const float*)d_in[18];

    char* ws = (char*)d_ws;
    unsigned short* xb   = (unsigned short*)(ws);                      // 8 MB
    unsigned short* W5t  = (unsigned short*)(ws + 8388608);            // 10 MB
    unsigned short* Wot  = (unsigned short*)(ws + 18874368);           // 2 MB
    float*          bias5= (float*)         (ws + 20971520);           // 20 KB
    unsigned short* cfb  = (unsigned short*)(ws + 20992000);           // 4 MB
    unsigned short* bfb  = (unsigned short*)(ws + 25186304);           // 4 MB
    unsigned short* Q5b  = (unsigned short*)(ws + 29380608);           // 40 MB
    unsigned short* Vtg  = (unsigned short*)(ws + 71323648);           // 8 MB
    unsigned short* ctxb = (unsigned short*)(ws + 79712256);           // 8 MB

    PrepArgs pa;
    pa.x = x; pa.pitch_pc = pitch_pc; pa.bass_pc = bass_pc;
    pa.Wc = Wc; pa.bc = bc; pa.Wb = Wb; pa.bb = bb;
    pa.wsrc[0] = Wpq; pa.wsrc[1] = Whq; pa.wsrc[2] = Wvq;
    pa.wsrc[3] = Wk;  pa.wsrc[4] = Wv;  pa.wsrc[5] = Wo;
    for (int i = 0; i < 5; ++i) pa.wdst[i] = W5t + (size_t)i * 1024 * 1024;
    pa.wdst[5] = Wot;
    pa.bsrc[0] = bpq; pa.bsrc[1] = bhq; pa.bsrc[2] = bvq; pa.bsrc[3] = bk; pa.bsrc[4] = bv;
    pa.bias5 = bias5; pa.xb = xb; pa.cfb = cfb; pa.bfb = bfb;

    prep_kernel<<<dim3(4096 + 1536 + 20 + 8192 + 8192), 256, 0, stream>>>(pa);

    gemm_k<0><<<dim3(40, 32), 256, 0, stream>>>(xb, W5t, bias5, Q5b, Vtg, nullptr);

    attn_kernel<<<dim3(B_ * H_, S_ / ATQ_), 512, 81920, stream>>>(Q5b, cfb, bfb, Vtg, ctxb);

    gemm_k<1><<<dim3(8, 32), 256, 0, stream>>>(ctxb, Wot, bo, nullptr, nullptr, (float*)d_out);
}